// Round 11
// baseline (369.219 us; speedup 1.0000x reference)
//
#include <hip/hip_runtime.h>
#include <hip/hip_bf16.h>

#define D      128
#define LG     9
#define CHUNK  512   // (1 << LG)

typedef __attribute__((ext_vector_type(8))) short          short8;
typedef __attribute__((ext_vector_type(8))) unsigned short ushort8;
typedef __attribute__((ext_vector_type(4))) float          floatx4;
typedef __attribute__((ext_vector_type(2))) float          floatx2;

__device__ inline float b2f(unsigned short u) {
    return __uint_as_float(((unsigned)u) << 16);
}
__device__ inline unsigned short f2bf(float f) {
    __hip_bfloat16 h = __float2bfloat16(f);
    unsigned short u;
    __builtin_memcpy(&u, &h, 2);
    return u;
}
__device__ inline short8 u2s(ushort8 u) {
    short8 s; __builtin_memcpy(&s, &u, 16); return s;
}
__device__ inline void atomicMaxF(float* addr, float v) {
    if (v >= 0.f) atomicMax((int*)addr, __float_as_int(v));
    else          atomicMin((unsigned int*)addr, __float_as_uint(v));
}

__global__ void init_out_kernel(float* out, int out_size) {
    int t = threadIdx.x;
    if (t < out_size) out[t] = -INFINITY;
}

// Pass 1 (FUSED): single gather pass. Chunk-LOCAL inclusive cumsum (fp32
// accum), bf16 NT stores, chunk totals -> sumE. One wave per chunk.
__global__ __launch_bounds__(128) void local_scan_kernel(
        const int* __restrict__ tokens, const float* __restrict__ emb,
        unsigned* __restrict__ T32, float* __restrict__ sumE, int n, int C) {
    __shared__ int toks[2][CHUNK];
    int tid = threadIdx.x, w = tid >> 6, lane = tid & 63;
    int cb = min(blockIdx.x * 2 + w, C - 1);   // tail duplicate: same bytes, benign
    int i0 = cb << LG, cnt = min(CHUNK, n - i0);
    for (int t = lane; t < cnt; t += 64) toks[w][t] = tokens[i0 + t];
    __syncthreads();
    const floatx2* eb = (const floatx2*)emb;   // emb row = 64 float2
    float rx = 0.f, ry = 0.f;
    unsigned* To = T32 + (size_t)i0 * 64 + lane;
    #pragma unroll 4
    for (int j = 0; j < cnt; ++j) {
        floatx2 v = eb[(size_t)toks[w][j] * 64 + lane];
        rx += v[0]; ry += v[1];
        unsigned pk = ((unsigned)f2bf(rx)) | (((unsigned)f2bf(ry)) << 16);
        __builtin_nontemporal_store(pk, To + (size_t)j * 64);
    }
    floatx2 rr = {rx, ry};
    *(floatx2*)(sumE + (size_t)cb * D + lane * 2) = rr;
}

// Pass 2: in-place exclusive scan of chunk totals (one wave per dim).
__global__ void scan_kernel(float* sumE, int C) {
    int d    = blockIdx.x;     // 0..127
    int lane = threadIdx.x;    // 0..63
    float carry = 0.f;
    for (int c0 = 0; c0 < C; c0 += 64) {
        int c = c0 + lane;
        float v = (c < C) ? sumE[(size_t)c * D + d] : 0.f;
        float incl = v;
        #pragma unroll
        for (int off = 1; off < 64; off <<= 1) {
            float t = __shfl_up(incl, off);
            if (lane >= off) incl += t;
        }
        if (c < C) sumE[(size_t)c * D + d] = carry + incl - v;  // exclusive
        carry += __shfl(incl, 63);
    }
}

// Pass 3: WP[c][d] = dot(W[d,:], pref[c,:]), IN PLACE over pref (each block
// reads only its own 16 rows before overwriting them). WP is ~1 MB, L2-hot.
__global__ __launch_bounds__(128) void wp_kernel(
        const float* __restrict__ W, float* __restrict__ P, int C) {
    __shared__ float pl[16][D];
    int d = threadIdx.x;
    int c0 = blockIdx.x * 16;
    int nr = min(16, C - c0);
    for (int r = 0; r < nr; ++r) pl[r][d] = P[(size_t)(c0 + r) * D + d];
    __syncthreads();
    float acc[16];
    #pragma unroll
    for (int r = 0; r < 16; ++r) acc[r] = 0.f;
    const float* wr = W + (size_t)d * D;
    for (int k = 0; k < D; ++k) {
        float wk = wr[k];
        #pragma unroll
        for (int r = 0; r < 16; ++r) acc[r] += wk * pl[r][k];
    }
    __syncthreads();
    for (int r = 0; r < nr; ++r) P[(size_t)(c0 + r) * D + d] = acc[r];
}

// Pass 4: h = (W*Sloc[e]) - (W*Sloc[i-1]) + (WP[ce]-WP[cp]) + cnt*b.
// Dual-MFMA on raw bf16 local-cumsum rows; fp32 WP correction on the output
// side, exec-mask-skipped when ce==cp (~91% of nodes). 2-deep pipeline,
// interleaved tile assignment (dense sliding window over S).
__global__ __launch_bounds__(256, 2) void max_pass_kernel(
        const int* __restrict__ ends, const unsigned short* __restrict__ S,
        const float* __restrict__ WP, const float* __restrict__ W,
        const float* __restrict__ bvec, float* __restrict__ out,
        int n, int tpw, int Cm1) {
    __shared__ float red[4][8][16];
    int tid = threadIdx.x, lane = tid & 63, wid = tid >> 6;
    int c  = lane & 15;   // node-in-tile / output-dim-in-tile
    int kg = lane >> 4;   // k-subgroup 0..3

    // Full W^T as bf16 fragments + bias.
    short8 Wf[8][4];
    float  bc[8];
    #pragma unroll
    for (int tl = 0; tl < 8; ++tl) {
        const float* wr = W + (size_t)(tl * 16 + c) * D + kg * 8;
        bc[tl] = bvec[tl * 16 + c];
        #pragma unroll
        for (int kk = 0; kk < 4; ++kk) {
            floatx4 f0 = *(const floatx4*)(wr + kk * 32);
            floatx4 f1 = *(const floatx4*)(wr + kk * 32 + 4);
            short8 w;
            #pragma unroll
            for (int j = 0; j < 4; ++j) { w[j] = (short)f2bf(f0[j]); w[j + 4] = (short)f2bf(f1[j]); }
            Wf[tl][kk] = w;
        }
    }
    float mx[8];
    #pragma unroll
    for (int tl = 0; tl < 8; ++tl) mx[tl] = -INFINITY;

    const ushort8* Sv = (const ushort8*)S;   // row = 16 granules of 8 bf16
    int gw = blockIdx.x * 4 + wid;
    int STRIDE = gridDim.x * 4;
    ushort8 zero8 = {0, 0, 0, 0, 0, 0, 0, 0};

#define TIDX(k)  (gw + (k) * STRIDE)
#define LD_E(k)  ends[min(TIDX(k) * 16 + c, n - 1)]
#define LOAD_ROWS(k, e, Pe, Pp) do {                                     \
        int node_ = TIDX(k) * 16 + c;                                    \
        int pc_ = max(min(node_, n) - 1, 0);                             \
        const ushort8* pe_ = Sv + (size_t)(e) * 16 + kg;                 \
        const ushort8* pp_ = Sv + (size_t)pc_ * 16 + kg;                 \
        Pe[0] = pe_[0]; Pe[1] = pe_[4]; Pe[2] = pe_[8]; Pe[3] = pe_[12]; \
        Pp[0] = pp_[0]; Pp[1] = pp_[4]; Pp[2] = pp_[8]; Pp[3] = pp_[12]; \
        if (node_ == 0) { Pp[0] = zero8; Pp[1] = zero8; Pp[2] = zero8; Pp[3] = zero8; } \
    } while (0)

#define PROCESS(k, e, Pe, Pp) do {                                       \
        int base_ = TIDX(k) * 16;                                        \
        floatx4 cnt4_;                                                   \
        int oe_[4], op_[4];                                              \
        _Pragma("unroll")                                                \
        for (int i = 0; i < 4; ++i) {                                    \
            int ei_ = __shfl((e), kg * 4 + i);                           \
            int nd_ = base_ + kg * 4 + i;                                 \
            cnt4_[i] = (float)(ei_ - nd_ + 1);                            \
            int ce_ = min(ei_ >> LG, Cm1);                                \
            int cp_ = min(max(nd_ - 1, 0) >> LG, Cm1);                    \
            oe_[i] = (ce_ << 7) + c;                                      \
            op_[i] = (cp_ << 7) + c;                                      \
        }                                                                \
        _Pragma("unroll")                                                \
        for (int tl = 0; tl < 8; ++tl) {                                 \
            floatx4 ae_ = {0.f, 0.f, 0.f, 0.f};                          \
            floatx4 ap_ = {0.f, 0.f, 0.f, 0.f};                          \
            _Pragma("unroll")                                            \
            for (int kk = 0; kk < 4; ++kk) {                             \
                ae_ = __builtin_amdgcn_mfma_f32_16x16x32_bf16(u2s(Pe[kk]), Wf[tl][kk], ae_, 0, 0, 0); \
                ap_ = __builtin_amdgcn_mfma_f32_16x16x32_bf16(u2s(Pp[kk]), Wf[tl][kk], ap_, 0, 0, 0); \
            }                                                            \
            _Pragma("unroll")                                            \
            for (int i = 0; i < 4; ++i) {                                \
                float corr_ = 0.f;                                       \
                if (oe_[i] != op_[i])                                    \
                    corr_ = WP[oe_[i] + tl * 16] - WP[op_[i] + tl * 16]; \
                float h_ = (ae_[i] - ap_[i]) + corr_ + cnt4_[i] * bc[tl];\
                if (base_ + kg * 4 + i < n) mx[tl] = fmaxf(mx[tl], h_);  \
            }                                                            \
        }                                                                \
    } while (0)

    ushort8 Ae[4], Ap[4], Be[4], Bp[4];
    int e0 = LD_E(0);
    LOAD_ROWS(0, e0, Ae, Ap);
    int e1 = LD_E(1);
    for (int k = 0; k < tpw; k += 2) {
        LOAD_ROWS(k + 1, e1, Be, Bp);
        int e2 = LD_E(k + 2);
        PROCESS(k, e0, Ae, Ap);
        LOAD_ROWS(k + 2, e2, Ae, Ap);
        int e3 = LD_E(k + 3);
        PROCESS(k + 1, e1, Be, Bp);
        e0 = e2; e1 = e3;
    }

    // Reduce across the 4 k-subgroups (same output dim tl*16+c).
    #pragma unroll
    for (int tl = 0; tl < 8; ++tl) {
        float v = mx[tl];
        v = fmaxf(v, __shfl_xor(v, 16));
        v = fmaxf(v, __shfl_xor(v, 32));
        mx[tl] = v;
    }
    if (kg == 0) {
        #pragma unroll
        for (int tl = 0; tl < 8; ++tl) red[wid][tl][c] = mx[tl];
    }
    __syncthreads();
    if (tid < 128) {
        int tl = tid >> 4, cc = tid & 15;
        float v = fmaxf(fmaxf(red[0][tl][cc], red[1][tl][cc]),
                        fmaxf(red[2][tl][cc], red[3][tl][cc]));
        atomicMaxF(&out[tl * 16 + cc], v);
    }
}

extern "C" void kernel_launch(void* const* d_in, const int* in_sizes, int n_in,
                              void* d_out, int out_size, void* d_ws, size_t ws_size,
                              hipStream_t stream) {
    const int*   tokens = (const int*)d_in[0];
    const int*   ends   = (const int*)d_in[1];
    const float* emb    = (const float*)d_in[2];
    const float* W      = (const float*)d_in[3];
    const float* bvec   = (const float*)d_in[4];
    float* out = (float*)d_out;
    int n = in_sizes[0];
    int C = (n + CHUNK - 1) >> LG;

    unsigned short* S    = (unsigned short*)d_ws;          // n*128 bf16 = 256 MB
    float*          sumE = (float*)(S + (size_t)n * D);    // C*128 fp32: totals -> pref -> WP (in place)
    // total = n*256 + C*512 = 257,000,448 B for n=1e6 (same proven footprint)

    init_out_kernel<<<1, 128, 0, stream>>>(out, out_size);
    local_scan_kernel<<<(C + 1) / 2, 128, 0, stream>>>(tokens, emb,
                                                       (unsigned*)S, sumE, n, C);
    scan_kernel<<<128, 64, 0, stream>>>(sumE, C);
    wp_kernel<<<(C + 15) / 16, 128, 0, stream>>>(W, sumE, C);

    int n_tiles = (n + 15) / 16;
    int nblocks = 512;                        // 2 blocks/CU, 2048 wave-streams
    int waves   = nblocks * 4;
    int tpw = ((n_tiles + waves - 1) / waves + 1) & ~1;   // even, tail masked
    max_pass_kernel<<<nblocks, 256, 0, stream>>>(ends, S, sumE, W, bvec, out,
                                                 n, tpw, C - 1);
}

// Round 12
// 273.000 us; speedup vs baseline: 1.3525x; 1.3525x over previous
//
#include <hip/hip_runtime.h>
#include <hip/hip_bf16.h>

#define D      128
#define LG     9
#define CHUNK  512   // (1 << LG)

typedef __attribute__((ext_vector_type(8))) short          short8;
typedef __attribute__((ext_vector_type(8))) unsigned short ushort8;
typedef __attribute__((ext_vector_type(4))) float          floatx4;
typedef __attribute__((ext_vector_type(2))) float          floatx2;

__device__ inline float b2f(unsigned short u) {
    return __uint_as_float(((unsigned)u) << 16);
}
__device__ inline unsigned short f2bf(float f) {
    __hip_bfloat16 h = __float2bfloat16(f);
    unsigned short u;
    __builtin_memcpy(&u, &h, 2);
    return u;
}
__device__ inline short8 u2s(ushort8 u) {
    short8 s; __builtin_memcpy(&s, &u, 16); return s;
}
__device__ inline void atomicMaxF(float* addr, float v) {
    if (v >= 0.f) atomicMax((int*)addr, __float_as_int(v));
    else          atomicMin((unsigned int*)addr, __float_as_uint(v));
}

__global__ void init_out_kernel(float* out, int out_size) {
    int t = threadIdx.x;
    if (t < out_size) out[t] = -INFINITY;
}

// Pass 1 (FUSED): single gather pass. Chunk-LOCAL inclusive cumsum (fp32
// accum), bf16 NT stores, chunk totals -> sumE. One wave per chunk.
__global__ __launch_bounds__(128) void local_scan_kernel(
        const int* __restrict__ tokens, const float* __restrict__ emb,
        unsigned* __restrict__ T32, float* __restrict__ sumE, int n, int C) {
    __shared__ int toks[2][CHUNK];
    int tid = threadIdx.x, w = tid >> 6, lane = tid & 63;
    int cb = min(blockIdx.x * 2 + w, C - 1);   // tail duplicate: same bytes, benign
    int i0 = cb << LG, cnt = min(CHUNK, n - i0);
    for (int t = lane; t < cnt; t += 64) toks[w][t] = tokens[i0 + t];
    __syncthreads();
    const floatx2* eb = (const floatx2*)emb;   // emb row = 64 float2
    float rx = 0.f, ry = 0.f;
    unsigned* To = T32 + (size_t)i0 * 64 + lane;
    #pragma unroll 4
    for (int j = 0; j < cnt; ++j) {
        floatx2 v = eb[(size_t)toks[w][j] * 64 + lane];
        rx += v[0]; ry += v[1];
        unsigned pk = ((unsigned)f2bf(rx)) | (((unsigned)f2bf(ry)) << 16);
        __builtin_nontemporal_store(pk, To + (size_t)j * 64);
    }
    floatx2 rr = {rx, ry};
    *(floatx2*)(sumE + (size_t)cb * D + lane * 2) = rr;
}

// Pass 2: exclusive scan of chunk totals (one wave per dim), fp32 in place
// plus bf16 row copy (prefB) for MFMA-side folding in max_pass.
__global__ void scan_kernel(float* sumE, unsigned short* prefB, int C) {
    int d    = blockIdx.x;     // 0..127
    int lane = threadIdx.x;    // 0..63
    float carry = 0.f;
    for (int c0 = 0; c0 < C; c0 += 64) {
        int c = c0 + lane;
        float v = (c < C) ? sumE[(size_t)c * D + d] : 0.f;
        float incl = v;
        #pragma unroll
        for (int off = 1; off < 64; off <<= 1) {
            float t = __shfl_up(incl, off);
            if (lane >= off) incl += t;
        }
        if (c < C) {
            float exc = carry + incl - v;        // exclusive prefix
            sumE[(size_t)c * D + d] = exc;
            prefB[(size_t)c * D + d] = f2bf(exc);
        }
        carry += __shfl(incl, 63);
    }
}

// Pass 3: h = [W*prefB[ce] + W*Sloc[e]] - [W*prefB[cp] + W*Sloc[p]] + cnt*b.
// Branch-free MFMA-fold of the chunk-prefix correction (prefB is L2-hot).
// Wave-pair: each wave holds half of W^T (64 VGPR); pair shares node tiles
// (S reads dedupe in L1). e-side rows 2-deep pipelined (scattered); p-side
// rows sequential, loaded at PROCESS start. Interleaved tile assignment.
__global__ __launch_bounds__(256, 2) void max_pass_kernel(
        const int* __restrict__ ends, const unsigned short* __restrict__ S,
        const unsigned short* __restrict__ prefB, const float* __restrict__ W,
        const float* __restrict__ bvec, float* __restrict__ out,
        int n, int tpw) {
    __shared__ float red[4][4][16];
    int tid = threadIdx.x, lane = tid & 63, wid = tid >> 6;
    int c  = lane & 15;   // node-in-tile / output-dim-in-tile
    int kg = lane >> 4;   // k-subgroup 0..3
    int tw = wid & 1;     // which half of the 8 output-tiles
    int pr = wid >> 1;    // pair id in block

    // This wave's half of W^T as bf16 fragments + bias.
    short8 Wf[4][4];
    float  bc[4];
    #pragma unroll
    for (int tl = 0; tl < 4; ++tl) {
        const float* wr = W + (size_t)((tw * 4 + tl) * 16 + c) * D + kg * 8;
        bc[tl] = bvec[(tw * 4 + tl) * 16 + c];
        #pragma unroll
        for (int kk = 0; kk < 4; ++kk) {
            floatx4 f0 = *(const floatx4*)(wr + kk * 32);
            floatx4 f1 = *(const floatx4*)(wr + kk * 32 + 4);
            short8 w;
            #pragma unroll
            for (int j = 0; j < 4; ++j) { w[j] = (short)f2bf(f0[j]); w[j + 4] = (short)f2bf(f1[j]); }
            Wf[tl][kk] = w;
        }
    }
    float mx[4];
    #pragma unroll
    for (int tl = 0; tl < 4; ++tl) mx[tl] = -INFINITY;

    const ushort8* Sv = (const ushort8*)S;       // row = 16 granules of 8 bf16
    const ushort8* PB = (const ushort8*)prefB;   // row = 16 granules of 8 bf16
    int gp = blockIdx.x * 2 + pr;
    int STRIDE = gridDim.x * 2;
    ushort8 zero8 = {0, 0, 0, 0, 0, 0, 0, 0};

#define TIDX(k)  (gp + (k) * STRIDE)
#define LD_E(k)  ends[min(TIDX(k) * 16 + c, n - 1)]
#define LOAD_EROWS(k, e, QE, SE) do {                                    \
        int ce_ = (e) >> LG;                                             \
        const ushort8* se_ = Sv + (size_t)(e) * 16 + kg;                 \
        const ushort8* qe_ = PB + (size_t)ce_ * 16 + kg;                 \
        SE[0] = se_[0]; SE[1] = se_[4]; SE[2] = se_[8]; SE[3] = se_[12]; \
        QE[0] = qe_[0]; QE[1] = qe_[4]; QE[2] = qe_[8]; QE[3] = qe_[12]; \
    } while (0)

#define PROCESS(k, e, QE, SE) do {                                       \
        int base_ = TIDX(k) * 16;                                        \
        int node_ = base_ + c;                                           \
        int pc_ = max(min(node_, n) - 1, 0);                             \
        int cp_ = pc_ >> LG;                                             \
        const ushort8* sp_ = Sv + (size_t)pc_ * 16 + kg;                 \
        const ushort8* qp_ = PB + (size_t)cp_ * 16 + kg;                 \
        ushort8 SP[4], QP[4];                                            \
        SP[0] = sp_[0]; SP[1] = sp_[4]; SP[2] = sp_[8]; SP[3] = sp_[12]; \
        QP[0] = qp_[0]; QP[1] = qp_[4]; QP[2] = qp_[8]; QP[3] = qp_[12]; \
        if (node_ == 0) { SP[0] = zero8; SP[1] = zero8; SP[2] = zero8; SP[3] = zero8; } \
        floatx4 cnt4_;                                                   \
        _Pragma("unroll")                                                \
        for (int i = 0; i < 4; ++i)                                      \
            cnt4_[i] = (float)(__shfl((e), kg * 4 + i) - (base_ + kg * 4 + i) + 1); \
        _Pragma("unroll")                                                \
        for (int tl = 0; tl < 4; ++tl) {                                 \
            floatx4 ae_ = {0.f, 0.f, 0.f, 0.f};                          \
            floatx4 ap_ = {0.f, 0.f, 0.f, 0.f};                          \
            _Pragma("unroll")                                            \
            for (int kk = 0; kk < 4; ++kk) {                             \
                ae_ = __builtin_amdgcn_mfma_f32_16x16x32_bf16(u2s(QE[kk]), Wf[tl][kk], ae_, 0, 0, 0); \
                ap_ = __builtin_amdgcn_mfma_f32_16x16x32_bf16(u2s(QP[kk]), Wf[tl][kk], ap_, 0, 0, 0); \
            }                                                            \
            _Pragma("unroll")                                            \
            for (int kk = 0; kk < 4; ++kk) {                             \
                ae_ = __builtin_amdgcn_mfma_f32_16x16x32_bf16(u2s(SE[kk]), Wf[tl][kk], ae_, 0, 0, 0); \
                ap_ = __builtin_amdgcn_mfma_f32_16x16x32_bf16(u2s(SP[kk]), Wf[tl][kk], ap_, 0, 0, 0); \
            }                                                            \
            _Pragma("unroll")                                            \
            for (int i = 0; i < 4; ++i) {                                \
                float h_ = (ae_[i] - ap_[i]) + cnt4_[i] * bc[tl];        \
                if (base_ + kg * 4 + i < n) mx[tl] = fmaxf(mx[tl], h_);  \
            }                                                            \
        }                                                                \
    } while (0)

    ushort8 QEa[4], SEa[4], QEb[4], SEb[4];
    int e0 = LD_E(0);
    LOAD_EROWS(0, e0, QEa, SEa);
    int e1 = LD_E(1);
    for (int k = 0; k < tpw; k += 2) {
        LOAD_EROWS(k + 1, e1, QEb, SEb);
        int e2 = LD_E(k + 2);
        PROCESS(k, e0, QEa, SEa);
        LOAD_EROWS(k + 2, e2, QEa, SEa);
        int e3 = LD_E(k + 3);
        PROCESS(k + 1, e1, QEb, SEb);
        e0 = e2; e1 = e3;
    }

    // Reduce across the 4 k-subgroups (same output dim (tw*4+tl)*16+c).
    #pragma unroll
    for (int tl = 0; tl < 4; ++tl) {
        float v = mx[tl];
        v = fmaxf(v, __shfl_xor(v, 16));
        v = fmaxf(v, __shfl_xor(v, 32));
        mx[tl] = v;
    }
    if (kg == 0) {
        #pragma unroll
        for (int tl = 0; tl < 4; ++tl) red[wid][tl][c] = mx[tl];
    }
    __syncthreads();
    if (tid < 128) {
        int twf = tid >> 6;          // waves {twf, twf+2} share tw = twf
        int tl  = (tid >> 4) & 3;
        int cc  = tid & 15;
        float v = fmaxf(red[twf][tl][cc], red[twf + 2][tl][cc]);
        atomicMaxF(&out[(twf * 4 + tl) * 16 + cc], v);
    }
}

extern "C" void kernel_launch(void* const* d_in, const int* in_sizes, int n_in,
                              void* d_out, int out_size, void* d_ws, size_t ws_size,
                              hipStream_t stream) {
    const int*   tokens = (const int*)d_in[0];
    const int*   ends   = (const int*)d_in[1];
    const float* emb    = (const float*)d_in[2];
    const float* W      = (const float*)d_in[3];
    const float* bvec   = (const float*)d_in[4];
    float* out = (float*)d_out;
    int n = in_sizes[0];
    int C = (n + CHUNK - 1) >> LG;

    unsigned short* S     = (unsigned short*)d_ws;           // n*128 bf16 = 256 MB
    float*          sumE  = (float*)(S + (size_t)n * D);     // C*128 fp32 (scanned in place)
    unsigned short* prefB = (unsigned short*)(sumE + (size_t)C * D);  // C*128 bf16
    // total = n*256 + C*512 + C*256 = 257,500,672 B for n=1e6 (< proven 258,000,384)

    init_out_kernel<<<1, 128, 0, stream>>>(out, out_size);
    local_scan_kernel<<<(C + 1) / 2, 128, 0, stream>>>(tokens, emb,
                                                       (unsigned*)S, sumE, n, C);
    scan_kernel<<<128, 64, 0, stream>>>(sumE, prefB, C);

    int n_tiles = (n + 15) / 16;
    int nblocks = 512;                        // 2 blocks/CU; 1024 pair-streams
    int pairs   = nblocks * 2;
    int tpw = ((n_tiles + pairs - 1) / pairs + 1) & ~1;   // even, tail masked
    max_pass_kernel<<<nblocks, 256, 0, stream>>>(ends, S, prefB, W, bvec, out,
                                                 n, tpw);
}